// Round 1
// baseline (436.826 us; speedup 1.0000x reference)
//
#include <hip/hip_runtime.h>
#include <math.h>

// Sinkhorn on [B=32, N=1024, N=1024] fp32, TAU=1, 10 iters.
// Key identity: log_s == s + r[b,i] + c[b,j] at every step.
//   even iter: r[b,i] = -LSE_j(s[b,i,j] + c[b,j])
//   odd  iter: c[b,j] = -LSE_i(s[b,i,j] + r[b,i])
// output = exp(s + r + c).

#define BATCH 32
#define N 1024
#define CHUNKS 8
#define ROWS_PER_CHUNK (N / CHUNKS)  // 128

__global__ __launch_bounds__(256) void zero_c_kernel(float* __restrict__ c) {
    int idx = blockIdx.x * 256 + threadIdx.x;
    c[idx] = 0.0f;  // grid sized exactly BATCH*N/256
}

// One wave per row. 16 elements/lane via 4x float4.
__global__ __launch_bounds__(256) void row_lse_kernel(const float* __restrict__ s,
                                                      const float* __restrict__ c,
                                                      float* __restrict__ r) {
    const int wave = threadIdx.x >> 6;
    const int lane = threadIdx.x & 63;
    const int row  = blockIdx.x * 4 + wave;   // 0..BATCH*N-1
    const int b    = row >> 10;

    const float4* __restrict__ srow = (const float4*)(s + (size_t)row * N);
    const float4* __restrict__ crow = (const float4*)(c + (size_t)b * N);

    float x[16];
#pragma unroll
    for (int k = 0; k < 4; k++) {
        float4 v  = srow[lane + k * 64];
        float4 cv = crow[lane + k * 64];
        x[4 * k + 0] = v.x + cv.x;
        x[4 * k + 1] = v.y + cv.y;
        x[4 * k + 2] = v.z + cv.z;
        x[4 * k + 3] = v.w + cv.w;
    }

    float m = x[0];
#pragma unroll
    for (int t = 1; t < 16; t++) m = fmaxf(m, x[t]);
#pragma unroll
    for (int off = 32; off > 0; off >>= 1) m = fmaxf(m, __shfl_xor(m, off, 64));

    float sum = 0.0f;
#pragma unroll
    for (int t = 0; t < 16; t++) sum += __expf(x[t] - m);
#pragma unroll
    for (int off = 32; off > 0; off >>= 1) sum += __shfl_xor(sum, off, 64);

    if (lane == 0) r[row] = -(m + __logf(sum));
}

// Online LSE down columns; each thread owns one column over a 128-row chunk.
__global__ __launch_bounds__(1024) void col_lse_partial_kernel(const float* __restrict__ s,
                                                               const float* __restrict__ r,
                                                               float* __restrict__ pm,
                                                               float* __restrict__ pl) {
    const int bc    = blockIdx.x;          // b*CHUNKS + chunk
    const int b     = bc >> 3;
    const int chunk = bc & (CHUNKS - 1);
    const int j     = threadIdx.x;

    __shared__ float rs[ROWS_PER_CHUNK];
    if (threadIdx.x < ROWS_PER_CHUNK)
        rs[threadIdx.x] = r[b * N + chunk * ROWS_PER_CHUNK + threadIdx.x];
    __syncthreads();

    const float* __restrict__ base =
        s + ((size_t)(b * N + chunk * ROWS_PER_CHUNK)) * N + j;

    float m = -3.0e38f, l = 0.0f;
#pragma unroll 4
    for (int i = 0; i < ROWS_PER_CHUNK; i++) {
        float x  = base[(size_t)i * N] + rs[i];
        float mn = fmaxf(m, x);
        l = l * __expf(m - mn) + __expf(x - mn);
        m = mn;
    }
    pm[bc * N + j] = m;
    pl[bc * N + j] = l;
}

__global__ __launch_bounds__(1024) void col_combine_kernel(const float* __restrict__ pm,
                                                           const float* __restrict__ pl,
                                                           float* __restrict__ c) {
    const int b = blockIdx.x;
    const int j = threadIdx.x;
    float M = -3.0e38f, L = 0.0f;
#pragma unroll
    for (int chunk = 0; chunk < CHUNKS; chunk++) {
        float m  = pm[(b * CHUNKS + chunk) * N + j];
        float l  = pl[(b * CHUNKS + chunk) * N + j];
        float mn = fmaxf(M, m);
        L = L * __expf(M - mn) + l * __expf(m - mn);
        M = mn;
    }
    c[b * N + j] = -(M + __logf(L));
}

// Fallback if ws is too small for partials: direct full-column online LSE.
__global__ __launch_bounds__(1024) void col_lse_direct_kernel(const float* __restrict__ s,
                                                              const float* __restrict__ r,
                                                              float* __restrict__ c) {
    const int b = blockIdx.x;
    const int j = threadIdx.x;
    const float* __restrict__ rb = r + b * N;
    const float* __restrict__ base = s + (size_t)b * N * N + j;
    float m = -3.0e38f, l = 0.0f;
    for (int i = 0; i < N; i++) {
        float x  = base[(size_t)i * N] + rb[i];
        float mn = fmaxf(m, x);
        l = l * __expf(m - mn) + __expf(x - mn);
        m = mn;
    }
    c[b * N + j] = -(m + __logf(l));
}

__global__ __launch_bounds__(256) void finalize_kernel(const float* __restrict__ s,
                                                       const float* __restrict__ r,
                                                       const float* __restrict__ c,
                                                       float* __restrict__ out) {
    const int f4  = blockIdx.x * 256 + threadIdx.x;  // float4 index, 8M total
    const int j4  = f4 & 255;
    const int row = f4 >> 8;
    const int b   = row >> 10;

    float4 v  = ((const float4*)s)[f4];
    float  rr = r[row];
    float4 cc = ((const float4*)c)[(b << 8) + j4];

    float4 o;
    o.x = __expf(v.x + rr + cc.x);
    o.y = __expf(v.y + rr + cc.y);
    o.z = __expf(v.z + rr + cc.z);
    o.w = __expf(v.w + rr + cc.w);
    ((float4*)out)[f4] = o;
}

extern "C" void kernel_launch(void* const* d_in, const int* in_sizes, int n_in,
                              void* d_out, int out_size, void* d_ws, size_t ws_size,
                              hipStream_t stream) {
    const float* s = (const float*)d_in[0];
    float* out = (float*)d_out;

    float* c  = (float*)d_ws;                 // BATCH*N
    float* r  = c + BATCH * N;                // BATCH*N
    float* pm = r + BATCH * N;                // BATCH*CHUNKS*N
    float* pl = pm + BATCH * CHUNKS * N;      // BATCH*CHUNKS*N

    const size_t needed = (size_t)(2 * BATCH * N + 2 * BATCH * CHUNKS * N) * sizeof(float);
    const bool use_partials = ws_size >= needed;

    zero_c_kernel<<<(BATCH * N) / 256, 256, 0, stream>>>(c);

    for (int it = 0; it < 10; it++) {
        if ((it & 1) == 0) {
            row_lse_kernel<<<(BATCH * N) / 4, 256, 0, stream>>>(s, c, r);
        } else if (use_partials) {
            col_lse_partial_kernel<<<BATCH * CHUNKS, 1024, 0, stream>>>(s, r, pm, pl);
            col_combine_kernel<<<BATCH, 1024, 0, stream>>>(pm, pl, c);
        } else {
            col_lse_direct_kernel<<<BATCH, 1024, 0, stream>>>(s, r, c);
        }
    }

    const int total_f4 = BATCH * N * N / 4;   // 8M
    finalize_kernel<<<total_f4 / 256, 256, 0, stream>>>(s, r, c, out);
}

// Round 2
// 431.711 us; speedup vs baseline: 1.0118x; 1.0118x over previous
//
#include <hip/hip_runtime.h>
#include <math.h>

// Sinkhorn [B=32, N=1024, N=1024] fp32, TAU=1, 10 iters.
// Identity: log_s == s + r[b,i] + c[b,j] always.
//   r = -LSE_j(s + c),  c = -LSE_i(s + r),  out = exp(s + r + c).
// Fused kernel does one (row, col-partial) pair in a single sweep of s.

#define BATCH 32
#define N 1024
#define RCHUNKS 32
#define ROWS_PER_BLK 32        // N / RCHUNKS
#define BGROUPS 2
#define ROWS_PER_GROUP 16      // ROWS_PER_BLK / BGROUPS
#define PCHUNKS RCHUNKS        // column partials per batch

// Fused: new r for this block's 32 rows, then column-partial online LSE
// over those rows with the fresh r. Grid = BATCH*RCHUNKS = 1024, block = 512.
__global__ __launch_bounds__(512, 4) void fused_pair_kernel(
    const float* __restrict__ s, const float* __restrict__ c,
    float* __restrict__ r, float* __restrict__ pm, float* __restrict__ pl,
    int has_c)
{
    const int bc    = blockIdx.x;          // b * RCHUNKS + chunk
    const int b     = bc >> 5;
    const int chunk = bc & 31;
    const int row0  = chunk * ROWS_PER_BLK;

    __shared__ float cs[N];
    __shared__ float rs[ROWS_PER_BLK];
    __shared__ float sm[BGROUPS][N];
    __shared__ float sl[BGROUPS][N];

    // stage c[b,:] (512 threads x float2)
    if (has_c) {
        ((float2*)cs)[threadIdx.x] = ((const float2*)(c + b * N))[threadIdx.x];
    } else {
        ((float2*)cs)[threadIdx.x] = make_float2(0.f, 0.f);
    }
    __syncthreads();

    // Phase A: row LSE. 8 waves, 4 rows each, 16 elems/lane.
    const int wave = threadIdx.x >> 6;
    const int lane = threadIdx.x & 63;
    const float4* cs4 = (const float4*)cs;
#pragma unroll
    for (int rp = 0; rp < 4; rp++) {
        const int row = wave * 4 + rp;
        const float4* srow = (const float4*)(s + ((size_t)(b * N + row0 + row)) * N);
        float x[16];
#pragma unroll
        for (int k = 0; k < 4; k++) {
            float4 v  = srow[lane + 64 * k];
            float4 cv = cs4[lane + 64 * k];
            x[4*k+0] = v.x + cv.x; x[4*k+1] = v.y + cv.y;
            x[4*k+2] = v.z + cv.z; x[4*k+3] = v.w + cv.w;
        }
        float m = x[0];
#pragma unroll
        for (int t = 1; t < 16; t++) m = fmaxf(m, x[t]);
#pragma unroll
        for (int off = 32; off > 0; off >>= 1) m = fmaxf(m, __shfl_xor(m, off, 64));
        float sum = 0.f;
#pragma unroll
        for (int t = 0; t < 16; t++) sum += __expf(x[t] - m);
#pragma unroll
        for (int off = 32; off > 0; off >>= 1) sum += __shfl_xor(sum, off, 64);
        if (lane == 0) {
            float rv = -(m + __logf(sum));
            rs[row] = rv;
            r[b * N + row0 + row] = rv;
        }
    }
    __syncthreads();

    // Phase B: column partial online LSE over this block's rows (+ fresh r).
    // 2 groups of 16 rows; thread owns 4 columns (float4), re-read hits L2/L3.
    const int j4 = threadIdx.x & 255;
    const int g  = threadIdx.x >> 8;
    const float4* sb4 = (const float4*)(s + ((size_t)(b * N + row0 + g * ROWS_PER_GROUP)) * N);
    float m0=-3.0e38f, m1=-3.0e38f, m2=-3.0e38f, m3=-3.0e38f;
    float l0=0.f, l1=0.f, l2=0.f, l3=0.f;
#pragma unroll
    for (int i = 0; i < ROWS_PER_GROUP; i++) {
        float ri = rs[g * ROWS_PER_GROUP + i];
        float4 v = sb4[(size_t)i * 256 + j4];
        float x0 = v.x + ri, x1 = v.y + ri, x2 = v.z + ri, x3 = v.w + ri;
        float n0 = fmaxf(m0, x0); l0 = l0 * __expf(m0 - n0) + __expf(x0 - n0); m0 = n0;
        float n1 = fmaxf(m1, x1); l1 = l1 * __expf(m1 - n1) + __expf(x1 - n1); m1 = n1;
        float n2 = fmaxf(m2, x2); l2 = l2 * __expf(m2 - n2) + __expf(x2 - n2); m2 = n2;
        float n3 = fmaxf(m3, x3); l3 = l3 * __expf(m3 - n3) + __expf(x3 - n3); m3 = n3;
    }
    ((float4*)sm[g])[j4] = make_float4(m0, m1, m2, m3);
    ((float4*)sl[g])[j4] = make_float4(l0, l1, l2, l3);
    __syncthreads();

    // merge the 2 groups, write one partial per column for this chunk
#pragma unroll
    for (int cc = 0; cc < 2; cc++) {
        const int col = threadIdx.x + cc * 512;
        float M = sm[0][col], L = sl[0][col];
        float m = sm[1][col], l = sl[1][col];
        float mn = fmaxf(M, m);
        L = L * __expf(M - mn) + l * __expf(m - mn);
        pm[(size_t)bc * N + col] = mn;
        pl[(size_t)bc * N + col] = L;
    }
}

// Combine 32 chunk-partials per column -> c. Grid = BATCH*4, block = 1024.
__global__ __launch_bounds__(1024) void col_combine_kernel(
    const float* __restrict__ pm, const float* __restrict__ pl,
    float* __restrict__ c)
{
    const int b  = blockIdx.x >> 2;
    const int q  = blockIdx.x & 3;
    const int jc = threadIdx.x & 255;
    const int kg = threadIdx.x >> 8;      // 0..3, 8 chunks each
    const int j  = q * 256 + jc;
    float M = -3.0e38f, L = 0.f;
#pragma unroll
    for (int k = 0; k < 8; k++) {
        const int kk = kg * 8 + k;
        float m = pm[((size_t)(b * PCHUNKS + kk)) * N + j];
        float l = pl[((size_t)(b * PCHUNKS + kk)) * N + j];
        float mn = fmaxf(M, m);
        L = L * __expf(M - mn) + l * __expf(m - mn); M = mn;
    }
    __shared__ float smm[4][256], sll[4][256];
    smm[kg][jc] = M; sll[kg][jc] = L;
    __syncthreads();
    if (kg == 0) {
#pragma unroll
        for (int g2 = 1; g2 < 4; g2++) {
            float m = smm[g2][jc], l = sll[g2][jc];
            float mn = fmaxf(M, m);
            L = L * __expf(M - mn) + l * __expf(m - mn); M = mn;
        }
        c[b * N + j] = -(M + __logf(L));
    }
}

// ---- fallback path (tiny workspace): round-1 style kernels ----
__global__ __launch_bounds__(256) void zero_c_kernel(float* __restrict__ c) {
    c[blockIdx.x * 256 + threadIdx.x] = 0.0f;
}

__global__ __launch_bounds__(256) void row_lse_kernel(const float* __restrict__ s,
                                                      const float* __restrict__ c,
                                                      float* __restrict__ r) {
    const int wave = threadIdx.x >> 6;
    const int lane = threadIdx.x & 63;
    const int row  = blockIdx.x * 4 + wave;
    const int b    = row >> 10;
    const float4* srow = (const float4*)(s + (size_t)row * N);
    const float4* crow = (const float4*)(c + (size_t)b * N);
    float x[16];
#pragma unroll
    for (int k = 0; k < 4; k++) {
        float4 v = srow[lane + k * 64];
        float4 cv = crow[lane + k * 64];
        x[4*k+0]=v.x+cv.x; x[4*k+1]=v.y+cv.y; x[4*k+2]=v.z+cv.z; x[4*k+3]=v.w+cv.w;
    }
    float m = x[0];
#pragma unroll
    for (int t = 1; t < 16; t++) m = fmaxf(m, x[t]);
#pragma unroll
    for (int off = 32; off > 0; off >>= 1) m = fmaxf(m, __shfl_xor(m, off, 64));
    float sum = 0.f;
#pragma unroll
    for (int t = 0; t < 16; t++) sum += __expf(x[t] - m);
#pragma unroll
    for (int off = 32; off > 0; off >>= 1) sum += __shfl_xor(sum, off, 64);
    if (lane == 0) r[row] = -(m + __logf(sum));
}

__global__ __launch_bounds__(1024) void col_lse_direct_kernel(const float* __restrict__ s,
                                                              const float* __restrict__ r,
                                                              float* __restrict__ c) {
    const int b = blockIdx.x;
    const int j = threadIdx.x;
    const float* rb = r + b * N;
    const float* base = s + (size_t)b * N * N + j;
    float m = -3.0e38f, l = 0.f;
    for (int i = 0; i < N; i++) {
        float x  = base[(size_t)i * N] + rb[i];
        float mn = fmaxf(m, x);
        l = l * __expf(m - mn) + __expf(x - mn);
        m = mn;
    }
    c[b * N + j] = -(m + __logf(l));
}
// ---- end fallback ----

__global__ __launch_bounds__(256) void finalize_kernel(const float* __restrict__ s,
                                                       const float* __restrict__ r,
                                                       const float* __restrict__ c,
                                                       float* __restrict__ out) {
    const int f4  = blockIdx.x * 256 + threadIdx.x;
    const int j4  = f4 & 255;
    const int row = f4 >> 8;
    const int b   = row >> 10;
    float4 v  = ((const float4*)s)[f4];
    float  rr = r[row];
    float4 cc = ((const float4*)c)[(b << 8) + j4];
    float4 o;
    o.x = __expf(v.x + rr + cc.x);
    o.y = __expf(v.y + rr + cc.y);
    o.z = __expf(v.z + rr + cc.z);
    o.w = __expf(v.w + rr + cc.w);
    ((float4*)out)[f4] = o;
}

extern "C" void kernel_launch(void* const* d_in, const int* in_sizes, int n_in,
                              void* d_out, int out_size, void* d_ws, size_t ws_size,
                              hipStream_t stream) {
    const float* s = (const float*)d_in[0];
    float* out = (float*)d_out;

    float* c  = (float*)d_ws;                       // BATCH*N
    float* r  = c + BATCH * N;                      // BATCH*N
    float* pm = r + BATCH * N;                      // BATCH*PCHUNKS*N
    float* pl = pm + BATCH * PCHUNKS * N;           // BATCH*PCHUNKS*N

    const size_t needed =
        (size_t)(2 * BATCH * N + 2 * BATCH * PCHUNKS * N) * sizeof(float);

    if (ws_size >= needed) {
        for (int p = 0; p < 5; p++) {
            fused_pair_kernel<<<BATCH * RCHUNKS, 512, 0, stream>>>(
                s, c, r, pm, pl, p > 0 ? 1 : 0);
            col_combine_kernel<<<BATCH * 4, 1024, 0, stream>>>(pm, pl, c);
        }
    } else {
        zero_c_kernel<<<(BATCH * N) / 256, 256, 0, stream>>>(c);
        for (int it = 0; it < 10; it++) {
            if ((it & 1) == 0)
                row_lse_kernel<<<(BATCH * N) / 4, 256, 0, stream>>>(s, c, r);
            else
                col_lse_direct_kernel<<<BATCH, 1024, 0, stream>>>(s, r, c);
        }
    }

    const int total_f4 = BATCH * N * N / 4;
    finalize_kernel<<<total_f4 / 256, 256, 0, stream>>>(s, r, c, out);
}